// Round 4
// baseline (596.734 us; speedup 1.0000x reference)
//
#include <hip/hip_runtime.h>
#include <math.h>

#define BB 2
#define CC 512
#define HEADS 2
#define DH 256
#define NWIN 64
#define LTOT 4096
#define TP 3
#define LP 3
#define SCALE 0.0625f

typedef short bf16x8 __attribute__((ext_vector_type(8)));
typedef float f32x4 __attribute__((ext_vector_type(4)));

__device__ __forceinline__ int refl8(int v) {
  v = v < 0 ? -v : v;
  return v >= 8 ? 14 - v : v;
}

__device__ __forceinline__ unsigned int bf16rne(float x) {
  unsigned int u = __float_as_uint(x);
  return (u + 0x7fffu + ((u >> 16) & 1u)) >> 16;
}

__device__ __forceinline__ float bf2f(unsigned short u) {
  return __uint_as_float(((unsigned int)u) << 16);
}

// Y[b,o,p] = sum_c W[o,c] * X[b,c,p] + bias[o]
__global__ __launch_bounds__(256) void conv1x1_kernel(
    const float* __restrict__ X, const float* __restrict__ Wm,
    const float* __restrict__ bias, float* __restrict__ Y, int Cout) {
  int blocksPerB = Cout >> 2;
  int b = blockIdx.x / blocksPerB;
  int ob = blockIdx.x - b * blocksPerB;
  int o = ob * 4 + (threadIdx.x >> 6);
  int p = threadIdx.x & 63;
  const float* xb = X + (size_t)b * CC * 64;
  const float* wr = Wm + (size_t)o * CC;
  float acc = 0.f;
#pragma unroll 8
  for (int c = 0; c < CC; ++c) acc += wr[c] * xb[c * 64 + p];
  Y[((size_t)b * Cout + o) * 64 + p] = acc + bias[o];
}

// One block per (b, win, head). Local window attention.
// Emits qgb (B,h,L,d) row-major bf16 AND qgT (B,h,d,L) dim-major bf16.
__global__ __launch_bounds__(256) void local_attn_kernel(
    const float* __restrict__ qkvx, const float* __restrict__ qkz,
    const float* __restrict__ pbeta, unsigned short* __restrict__ qgb,
    unsigned short* __restrict__ qgT) {
  __shared__ float kbuf[128 * 64];
  __shared__ float att[64 * 65];
  __shared__ float red[4 * 64];
  int bid = blockIdx.x;
  int b = bid >> 7;
  int win = (bid & 127) >> 1;
  int head = bid & 1;
  int tid = threadIdx.x;
  int t = tid & 63;
  int w4 = tid >> 6;
  int wi = win >> 3, wj = win & 7;
  int ry = refl8(wi + (t >> 3) - TP);
  int rx = refl8(wj + (t & 7) - LP);
  int pix = ry * 8 + rx;
  float beta = log1pf(__expf(pbeta[0])) + 1e-6f;

  const float* qxb = qkvx + (size_t)(b * 1536 + head * DH) * 64;
  const float* kxb = qkvx + (size_t)(b * 1536 + 512 + head * DH) * 64;
  const float* vxb = qkvx + (size_t)(b * 1536 + 1024 + head * DH) * 64;
  const float* qzb = qkz + (size_t)(b * 1024 + head * DH) * 64;
  const float* kzb = qkz + (size_t)(b * 1024 + 512 + head * DH) * 64;

  float dots[16];
#pragma unroll
  for (int s = 0; s < 16; ++s) dots[s] = 0.f;
#pragma unroll
  for (int hf = 0; hf < 2; ++hf) {
    __syncthreads();
    for (int i = 0; i < 32; ++i) {
      int dd = i * 4 + w4;
      kbuf[dd * 64 + t] = kxb[(hf * 128 + dd) * 64 + pix];
    }
    __syncthreads();
    for (int dd = 0; dd < 128; ++dd) {
      float qv = qxb[(hf * 128 + dd) * 64 + pix];
#pragma unroll
      for (int s = 0; s < 16; ++s)
        dots[s] += qv * kbuf[dd * 64 + w4 * 16 + s];
    }
  }
#pragma unroll
  for (int s = 0; s < 16; ++s) att[t * 65 + w4 * 16 + s] = dots[s];
#pragma unroll
  for (int s = 0; s < 16; ++s) dots[s] = 0.f;
#pragma unroll
  for (int hf = 0; hf < 2; ++hf) {
    __syncthreads();
    for (int i = 0; i < 32; ++i) {
      int dd = i * 4 + w4;
      kbuf[dd * 64 + t] = kzb[(hf * 128 + dd) * 64 + pix];
    }
    __syncthreads();
    for (int dd = 0; dd < 128; ++dd) {
      float qv = qzb[(hf * 128 + dd) * 64 + pix];
#pragma unroll
      for (int s = 0; s < 16; ++s)
        dots[s] += qv * kbuf[dd * 64 + w4 * 16 + s];
    }
  }
  // combine logits in regs, wave-parallel softmax over all 256 threads
  float vals[16];
  __syncthreads();
#pragma unroll
  for (int s = 0; s < 16; ++s)
    vals[s] = SCALE * (att[t * 65 + w4 * 16 + s] + beta * dots[s]);
  float mymax = -1e30f;
#pragma unroll
  for (int s = 0; s < 16; ++s) mymax = fmaxf(mymax, vals[s]);
  red[w4 * 64 + t] = mymax;
  __syncthreads();
  float m = fmaxf(fmaxf(red[t], red[64 + t]), fmaxf(red[128 + t], red[192 + t]));
  float mysum = 0.f;
#pragma unroll
  for (int s = 0; s < 16; ++s) {
    float e = __expf(vals[s] - m);
    vals[s] = e;
    mysum += e;
  }
  __syncthreads();
  red[w4 * 64 + t] = mysum;
  __syncthreads();
  float den = red[t] + red[64 + t] + red[128 + t] + red[192 + t];
  float rr = 1.f / den;
#pragma unroll
  for (int s = 0; s < 16; ++s) att[t * 65 + w4 * 16 + s] = vals[s] * rr;

  float acc[64];
#pragma unroll
  for (int j = 0; j < 64; ++j) acc[j] = 0.f;
#pragma unroll
  for (int hf = 0; hf < 2; ++hf) {
    __syncthreads();
    for (int i = 0; i < 32; ++i) {
      int dd = i * 4 + w4;
      kbuf[dd * 64 + t] = vxb[(hf * 128 + dd) * 64 + pix];
    }
    __syncthreads();
    for (int s = 0; s < 64; ++s) {
      float av = att[t * 65 + s];
#pragma unroll
      for (int j = 0; j < 32; ++j)
        acc[hf * 32 + j] += av * kbuf[(w4 * 32 + j) * 64 + s];
    }
  }
  int bh = b * HEADS + head;
  unsigned short* dst = qgb + ((size_t)(bh * LTOT + win * 64 + t)) * DH;
  unsigned short* dstT = qgT + (size_t)bh * DH * LTOT + (size_t)win * 64 + t;
#pragma unroll
  for (int j = 0; j < 32; ++j) {
    int d0 = w4 * 32 + j;
    unsigned short v0 = (unsigned short)bf16rne(acc[j]);
    unsigned short v1 = (unsigned short)bf16rne(acc[32 + j]);
    dst[d0] = v0;
    dst[128 + d0] = v1;
    dstT[(size_t)d0 * LTOT] = v0;
    dstT[(size_t)(128 + d0) * LTOT] = v1;
  }
}

// Global flash attention, split-K 2-way, 2 waves/block, 32 queries/wave.
// Each K/V fragment read from LDS feeds 2 MFMAs (two query groups).
__global__ __launch_bounds__(128, 2) void gattn_mfma(
    const unsigned short* __restrict__ qgb, const unsigned short* __restrict__ qgT,
    unsigned short* __restrict__ ogp, float2* __restrict__ ml) {
  __shared__ unsigned short krow[32 * 256];     // 16 KB, XOR-swizzled rows
  __shared__ unsigned short vt[256 * 36];       // 18 KB, [dim][key], 72 B stride
  __shared__ unsigned short plds[2 * 2 * 16 * 36];  // 4.5 KB, [wave][grp][q][key]
  int split = blockIdx.x & 1;
  int qt = (blockIdx.x >> 1) & 63;
  int bh = blockIdx.x >> 7;
  int qtile = qt * 64;
  int tid = threadIdx.x;
  int wave = tid >> 6;
  int lane = tid & 63;
  int lrow = lane & 15;
  int g = lane >> 4;
  const unsigned short* base = qgb + (size_t)bh * LTOT * DH;
  const unsigned short* baseT = qgT + (size_t)bh * DH * LTOT;
  char* krowc = (char*)krow;
  char* vtc = (char*)vt;
  char* plc0 = (char*)plds + wave * (2 * 16 * 72);
  char* plc1 = plc0 + 16 * 72;

  int qbase = qtile + wave * 32;
  int qi0 = qbase + lrow;
  int qi1 = qbase + 16 + lrow;
  bf16x8 qf0[8], qf1[8];
#pragma unroll
  for (int s = 0; s < 8; ++s) {
    qf0[s] = *(const bf16x8*)(base + (size_t)qi0 * DH + s * 32 + g * 8);
    qf1[s] = *(const bf16x8*)(base + (size_t)qi1 * DH + s * 32 + g * 8);
  }

  f32x4 acc0[16], acc1[16];
#pragma unroll
  for (int f = 0; f < 16; ++f) {
    acc0[f] = (f32x4){0.f, 0.f, 0.f, 0.f};
    acc1[f] = (f32x4){0.f, 0.f, 0.f, 0.f};
  }
  float m0 = -1e30f, l0 = 0.f, m1 = -1e30f, l1 = 0.f;

  for (int kt = split * 64; kt < split * 64 + 64; ++kt) {
    const unsigned short* kb = base + (size_t)kt * 32 * DH;
    __syncthreads();
    // ---- stage K row-major swizzled (1024 chunks of 16 B over 128 threads) ----
#pragma unroll
    for (int i = 0; i < 8; ++i) {
      int e = i * 128 + tid;
      int key = e >> 5, db = e & 31;
      bf16x8 v = *(const bf16x8*)(kb + key * DH + db * 8);
      *(bf16x8*)(krowc + key * 512 + ((db * 16) ^ ((key & 7) << 4))) = v;
    }
    // ---- stage V [dim][key] from qgT, 72 B stride ----
#pragma unroll
    for (int i = 0; i < 8; ++i) {
      int e = i * 128 + tid;
      int dim = e >> 2, ch = e & 3;
      bf16x8 v = *(const bf16x8*)(baseT + (size_t)dim * LTOT + kt * 32 + ch * 8);
      *(bf16x8*)(vtc + dim * 72 + ch * 16) = v;
    }
    __syncthreads();
    // ---- S^T = K * Q^T : 32 MFMAs from 16 K-frag reads ----
    f32x4 s00 = (f32x4){0.f, 0.f, 0.f, 0.f}, s01 = s00, s10 = s00, s11 = s00;
    int sw = (lrow & 7) << 4;
#pragma unroll
    for (int s = 0; s < 8; ++s) {
      bf16x8 k0 = *(const bf16x8*)(krowc + lrow * 512 + ((g * 16 + 64 * s) ^ sw));
      bf16x8 k1 = *(const bf16x8*)(krowc + (16 + lrow) * 512 + ((g * 16 + 64 * s) ^ sw));
      s00 = __builtin_amdgcn_mfma_f32_16x16x32_bf16(k0, qf0[s], s00, 0, 0, 0);
      s01 = __builtin_amdgcn_mfma_f32_16x16x32_bf16(k0, qf1[s], s01, 0, 0, 0);
      s10 = __builtin_amdgcn_mfma_f32_16x16x32_bf16(k1, qf0[s], s10, 0, 0, 0);
      s11 = __builtin_amdgcn_mfma_f32_16x16x32_bf16(k1, qf1[s], s11, 0, 0, 0);
    }
    // ---- online softmax, group 0 ----
    {
      float tmax = -1e30f;
#pragma unroll
      for (int r = 0; r < 4; ++r) {
        tmax = fmaxf(tmax, s00[r]);
        tmax = fmaxf(tmax, s10[r]);
      }
      tmax = fmaxf(tmax, __shfl_xor(tmax, 16, 64));
      tmax = fmaxf(tmax, __shfl_xor(tmax, 32, 64));
      float sm = tmax * SCALE;
      if (__any(sm > m0 + 6.f)) {
        float mn = fmaxf(m0, sm);
        float corr = __expf(m0 - mn);
#pragma unroll
        for (int f = 0; f < 16; ++f) {
          acc0[f][0] *= corr; acc0[f][1] *= corr;
          acc0[f][2] *= corr; acc0[f][3] *= corr;
        }
        l0 *= corr;
        m0 = mn;
      }
      float p[8], psum = 0.f;
#pragma unroll
      for (int r = 0; r < 4; ++r) {
        p[r] = __expf(s00[r] * SCALE - m0);
        p[4 + r] = __expf(s10[r] * SCALE - m0);
        psum += p[r] + p[4 + r];
      }
      psum += __shfl_xor(psum, 16, 64);
      psum += __shfl_xor(psum, 32, 64);
      l0 += psum;
      uint2 pk0, pk1;
      pk0.x = bf16rne(p[0]) | (bf16rne(p[1]) << 16);
      pk0.y = bf16rne(p[2]) | (bf16rne(p[3]) << 16);
      pk1.x = bf16rne(p[4]) | (bf16rne(p[5]) << 16);
      pk1.y = bf16rne(p[6]) | (bf16rne(p[7]) << 16);
      *(uint2*)(plc0 + lrow * 72 + g * 8) = pk0;
      *(uint2*)(plc0 + lrow * 72 + 32 + g * 8) = pk1;
    }
    // ---- online softmax, group 1 ----
    {
      float tmax = -1e30f;
#pragma unroll
      for (int r = 0; r < 4; ++r) {
        tmax = fmaxf(tmax, s01[r]);
        tmax = fmaxf(tmax, s11[r]);
      }
      tmax = fmaxf(tmax, __shfl_xor(tmax, 16, 64));
      tmax = fmaxf(tmax, __shfl_xor(tmax, 32, 64));
      float sm = tmax * SCALE;
      if (__any(sm > m1 + 6.f)) {
        float mn = fmaxf(m1, sm);
        float corr = __expf(m1 - mn);
#pragma unroll
        for (int f = 0; f < 16; ++f) {
          acc1[f][0] *= corr; acc1[f][1] *= corr;
          acc1[f][2] *= corr; acc1[f][3] *= corr;
        }
        l1 *= corr;
        m1 = mn;
      }
      float p[8], psum = 0.f;
#pragma unroll
      for (int r = 0; r < 4; ++r) {
        p[r] = __expf(s01[r] * SCALE - m1);
        p[4 + r] = __expf(s11[r] * SCALE - m1);
        psum += p[r] + p[4 + r];
      }
      psum += __shfl_xor(psum, 16, 64);
      psum += __shfl_xor(psum, 32, 64);
      l1 += psum;
      uint2 pk0, pk1;
      pk0.x = bf16rne(p[0]) | (bf16rne(p[1]) << 16);
      pk0.y = bf16rne(p[2]) | (bf16rne(p[3]) << 16);
      pk1.x = bf16rne(p[4]) | (bf16rne(p[5]) << 16);
      pk1.y = bf16rne(p[6]) | (bf16rne(p[7]) << 16);
      *(uint2*)(plc1 + lrow * 72 + g * 8) = pk0;
      *(uint2*)(plc1 + lrow * 72 + 32 + g * 8) = pk1;
    }
    asm volatile("s_waitcnt lgkmcnt(0)" ::: "memory");
    // ---- O^T += V^T * P : 32 MFMAs from 16 V-frag reads ----
    bf16x8 pf0 = *(const bf16x8*)(plc0 + lrow * 72 + g * 16);
    bf16x8 pf1 = *(const bf16x8*)(plc1 + lrow * 72 + g * 16);
#pragma unroll
    for (int f = 0; f < 16; ++f) {
      int dim = f * 16 + lrow;
      bf16x8 vf = *(const bf16x8*)(vtc + dim * 72 + g * 16);
      acc0[f] = __builtin_amdgcn_mfma_f32_16x16x32_bf16(vf, pf0, acc0[f], 0, 0, 0);
      acc1[f] = __builtin_amdgcn_mfma_f32_16x16x32_bf16(vf, pf1, acc1[f], 0, 0, 0);
    }
  }
  // ---- epilogue: unnormalized partial O (bf16) + (m,l) per query ----
  unsigned short* dst0 = ogp + ((size_t)(split * 4 + bh) * LTOT + qi0) * DH;
  unsigned short* dst1 = ogp + ((size_t)(split * 4 + bh) * LTOT + qi1) * DH;
#pragma unroll
  for (int f = 0; f < 16; ++f) {
    uint2 pk;
    pk.x = bf16rne(acc0[f][0]) | (bf16rne(acc0[f][1]) << 16);
    pk.y = bf16rne(acc0[f][2]) | (bf16rne(acc0[f][3]) << 16);
    *(uint2*)(dst0 + f * 16 + g * 4) = pk;
    pk.x = bf16rne(acc1[f][0]) | (bf16rne(acc1[f][1]) << 16);
    pk.y = bf16rne(acc1[f][2]) | (bf16rne(acc1[f][3]) << 16);
    *(uint2*)(dst1 + f * 16 + g * 4) = pk;
  }
  if (g == 0) {
    ml[(size_t)(split * 4 + bh) * LTOT + qi0] = make_float2(m0, l0);
    ml[(size_t)(split * 4 + bh) * LTOT + qi1] = make_float2(m1, l1);
  }
}

// Per-query combine weights for the 2 key-splits.
__global__ __launch_bounds__(256) void comb_kernel(
    const float2* __restrict__ ml, float2* __restrict__ comb) {
  int idx = blockIdx.x * 256 + threadIdx.x;  // 16384
  float2 a = ml[idx];
  float2 b = ml[16384 + idx];
  float M = fmaxf(a.x, b.x);
  float w0 = __expf(a.x - M), w1 = __expf(b.x - M);
  float r = 1.f / (a.y * w0 + b.y * w1);
  comb[idx] = make_float2(w0 * r, w1 * r);
}

// Combine splits + overlap-add gather + crop -> crop (B,C,64)
__global__ __launch_bounds__(256) void overlap_kernel(
    const unsigned short* __restrict__ ogp, const float2* __restrict__ comb,
    float* __restrict__ crop) {
  int idx = blockIdx.x * 256 + threadIdx.x;
  int dim = idx & 255;
  int r = idx >> 8;
  int p = r & 63;
  int head = (r >> 6) & 1;
  int b = r >> 7;
  int bh = b * 2 + head;
  int y = p >> 3, x = p & 7;
  int py = y + TP, px = x + LP;
  int i0 = max(0, py - 7), i1 = min(7, py);
  int j0 = max(0, px - 7), j1 = min(7, px);
  float s = 0.f;
  for (int iw = i0; iw <= i1; ++iw)
    for (int jw = j0; jw <= j1; ++jw) {
      int tok = (py - iw) * 8 + (px - jw);
      int q = (iw * 8 + jw) * 64 + tok;
      float2 cb = comb[bh * 4096 + q];
      size_t e = ((size_t)bh * 4096 + q) * 256 + dim;
      float o0 = bf2f(ogp[e]);
      float o1 = bf2f(ogp[(size_t)4 * LTOT * DH + e]);
      s += cb.x * o0 + cb.y * o1;
    }
  float cnt = (float)((i1 - i0 + 1) * (j1 - j0 + 1));
  crop[((size_t)b * CC + head * DH + dim) * 64 + p] = s / (cnt + 1e-6f);
}

// out = x_feat + a * (Wproj @ crop + bproj)
__global__ __launch_bounds__(256) void final_kernel(
    const float* __restrict__ crop, const float* __restrict__ Wp,
    const float* __restrict__ bp, const float* __restrict__ x_feat,
    const float* __restrict__ pa, float* __restrict__ out) {
  int blocksPerB = CC >> 2;
  int b = blockIdx.x / blocksPerB;
  int ob = blockIdx.x - b * blocksPerB;
  int o = ob * 4 + (threadIdx.x >> 6);
  int p = threadIdx.x & 63;
  float a = 2.f / (1.f + __expf(-pa[0]));
  const float* xb = crop + (size_t)b * CC * 64;
  const float* wr = Wp + (size_t)o * CC;
  float acc = 0.f;
#pragma unroll 8
  for (int c = 0; c < CC; ++c) acc += wr[c] * xb[c * 64 + p];
  size_t oi = ((size_t)b * CC + o) * 64 + p;
  out[oi] = x_feat[oi] + a * (acc + bp[o]);
}

extern "C" void kernel_launch(void* const* d_in, const int* in_sizes, int n_in,
                              void* d_out, int out_size, void* d_ws, size_t ws_size,
                              hipStream_t stream) {
  const float* x_feat = (const float*)d_in[0];
  const float* z_feat = (const float*)d_in[1];
  const float* Wqkv = (const float*)d_in[2];
  const float* bqkv = (const float*)d_in[3];
  const float* Wqkz = (const float*)d_in[4];
  const float* bqkz = (const float*)d_in[5];
  const float* Wproj = (const float*)d_in[6];
  const float* bproj = (const float*)d_in[7];
  const float* pa = (const float*)d_in[8];
  const float* pbeta = (const float*)d_in[9];
  float* ws = (float*)d_ws;
  float* qkvx = ws;                                        // 196608
  float* qkz = ws + 196608;                                // 131072
  unsigned short* qgb = (unsigned short*)(ws + 327680);    // 2097152 f
  unsigned short* qgT = (unsigned short*)(ws + 2424832);   // 2097152 f
  unsigned short* ogp = (unsigned short*)(ws + 4521984);   // 4194304 f (2 splits bf16)
  float2* ml = (float2*)(ws + 8716288);                    // 65536 f
  float* crop = ws;                                        // alias qkvx (dead after local_attn)
  float2* comb = (float2*)(ws + 196608);                   // alias qkz (dead after local_attn)
  float* out = (float*)d_out;

  conv1x1_kernel<<<BB * (1536 / 4), 256, 0, stream>>>(x_feat, Wqkv, bqkv, qkvx, 1536);
  conv1x1_kernel<<<BB * (1024 / 4), 256, 0, stream>>>(z_feat, Wqkz, bqkz, qkz, 1024);
  local_attn_kernel<<<256, 256, 0, stream>>>(qkvx, qkz, pbeta, qgb, qgT);
  gattn_mfma<<<512, 128, 0, stream>>>(qgb, qgT, ogp, ml);
  comb_kernel<<<64, 256, 0, stream>>>(ml, comb);
  overlap_kernel<<<256, 256, 0, stream>>>(ogp, comb, crop);
  final_kernel<<<BB * (CC / 4), 256, 0, stream>>>(crop, Wproj, bproj, x_feat, pa, out);
}

// Round 5
// 336.795 us; speedup vs baseline: 1.7718x; 1.7718x over previous
//
#include <hip/hip_runtime.h>
#include <math.h>

#define BB 2
#define CC 512
#define HEADS 2
#define DH 256
#define NWIN 64
#define LTOT 4096
#define TP 3
#define LP 3
#define SCALE 0.0625f

typedef short bf16x8 __attribute__((ext_vector_type(8)));
typedef float f32x4 __attribute__((ext_vector_type(4)));

__device__ __forceinline__ int refl8(int v) {
  v = v < 0 ? -v : v;
  return v >= 8 ? 14 - v : v;
}

__device__ __forceinline__ unsigned int bf16rne(float x) {
  unsigned int u = __float_as_uint(x);
  return (u + 0x7fffu + ((u >> 16) & 1u)) >> 16;
}

__device__ __forceinline__ float bf2f(unsigned short u) {
  return __uint_as_float(((unsigned int)u) << 16);
}

// Y[b,o,p] = sum_c W[o,c] * X[b,c,p] + bias[o]
__global__ __launch_bounds__(256) void conv1x1_kernel(
    const float* __restrict__ X, const float* __restrict__ Wm,
    const float* __restrict__ bias, float* __restrict__ Y, int Cout) {
  int blocksPerB = Cout >> 2;
  int b = blockIdx.x / blocksPerB;
  int ob = blockIdx.x - b * blocksPerB;
  int o = ob * 4 + (threadIdx.x >> 6);
  int p = threadIdx.x & 63;
  const float* xb = X + (size_t)b * CC * 64;
  const float* wr = Wm + (size_t)o * CC;
  float acc = 0.f;
#pragma unroll 8
  for (int c = 0; c < CC; ++c) acc += wr[c] * xb[c * 64 + p];
  Y[((size_t)b * Cout + o) * 64 + p] = acc + bias[o];
}

// One block per (b, win, head). Local window attention.
// Emits qgb (B,h,L,d) row-major bf16 AND qgT (B,h,d,L) dim-major bf16.
__global__ __launch_bounds__(256) void local_attn_kernel(
    const float* __restrict__ qkvx, const float* __restrict__ qkz,
    const float* __restrict__ pbeta, unsigned short* __restrict__ qgb,
    unsigned short* __restrict__ qgT) {
  __shared__ float kbuf[128 * 64];
  __shared__ float att[64 * 65];
  __shared__ float red[4 * 64];
  __shared__ float vbuf[64 * 132];  // [token][dim-half], pad 132 for write spread
  int bid = blockIdx.x;
  int b = bid >> 7;
  int win = (bid & 127) >> 1;
  int head = bid & 1;
  int tid = threadIdx.x;
  int t = tid & 63;
  int w4 = tid >> 6;
  int wi = win >> 3, wj = win & 7;
  int ry = refl8(wi + (t >> 3) - TP);
  int rx = refl8(wj + (t & 7) - LP);
  int pix = ry * 8 + rx;
  float beta = log1pf(__expf(pbeta[0])) + 1e-6f;

  const float* qxb = qkvx + (size_t)(b * 1536 + head * DH) * 64;
  const float* kxb = qkvx + (size_t)(b * 1536 + 512 + head * DH) * 64;
  const float* vxb = qkvx + (size_t)(b * 1536 + 1024 + head * DH) * 64;
  const float* qzb = qkz + (size_t)(b * 1024 + head * DH) * 64;
  const float* kzb = qkz + (size_t)(b * 1024 + 512 + head * DH) * 64;

  float dots[16];
#pragma unroll
  for (int s = 0; s < 16; ++s) dots[s] = 0.f;
#pragma unroll
  for (int hf = 0; hf < 2; ++hf) {
    __syncthreads();
    for (int i = 0; i < 32; ++i) {
      int dd = i * 4 + w4;
      kbuf[dd * 64 + t] = kxb[(hf * 128 + dd) * 64 + pix];
    }
    __syncthreads();
    for (int dd = 0; dd < 128; ++dd) {
      float qv = qxb[(hf * 128 + dd) * 64 + pix];
#pragma unroll
      for (int s = 0; s < 16; ++s)
        dots[s] += qv * kbuf[dd * 64 + w4 * 16 + s];
    }
  }
#pragma unroll
  for (int s = 0; s < 16; ++s) att[t * 65 + w4 * 16 + s] = dots[s];
#pragma unroll
  for (int s = 0; s < 16; ++s) dots[s] = 0.f;
#pragma unroll
  for (int hf = 0; hf < 2; ++hf) {
    __syncthreads();
    for (int i = 0; i < 32; ++i) {
      int dd = i * 4 + w4;
      kbuf[dd * 64 + t] = kzb[(hf * 128 + dd) * 64 + pix];
    }
    __syncthreads();
    for (int dd = 0; dd < 128; ++dd) {
      float qv = qzb[(hf * 128 + dd) * 64 + pix];
#pragma unroll
      for (int s = 0; s < 16; ++s)
        dots[s] += qv * kbuf[dd * 64 + w4 * 16 + s];
    }
  }
  // combine logits in regs, block-parallel softmax
  float vals[16];
  __syncthreads();
#pragma unroll
  for (int s = 0; s < 16; ++s)
    vals[s] = SCALE * (att[t * 65 + w4 * 16 + s] + beta * dots[s]);
  float mymax = -1e30f;
#pragma unroll
  for (int s = 0; s < 16; ++s) mymax = fmaxf(mymax, vals[s]);
  red[w4 * 64 + t] = mymax;
  __syncthreads();
  float m = fmaxf(fmaxf(red[t], red[64 + t]), fmaxf(red[128 + t], red[192 + t]));
  float mysum = 0.f;
#pragma unroll
  for (int s = 0; s < 16; ++s) {
    float e = __expf(vals[s] - m);
    vals[s] = e;
    mysum += e;
  }
  __syncthreads();
  red[w4 * 64 + t] = mysum;
  __syncthreads();
  float den = red[t] + red[64 + t] + red[128 + t] + red[192 + t];
  float rr = 1.f / den;
#pragma unroll
  for (int s = 0; s < 16; ++s) att[t * 65 + w4 * 16 + s] = vals[s] * rr;

  float acc[64];
#pragma unroll
  for (int j = 0; j < 64; ++j) acc[j] = 0.f;
#pragma unroll
  for (int hf = 0; hf < 2; ++hf) {
    __syncthreads();
    for (int i = 0; i < 32; ++i) {
      int dd = i * 4 + w4;
      vbuf[t * 132 + dd] = vxb[(hf * 128 + dd) * 64 + pix];
    }
    __syncthreads();
    for (int s = 0; s < 64; ++s) {
      float av = att[t * 65 + s];
      const float4* vrow = (const float4*)&vbuf[s * 132 + w4 * 32];
#pragma unroll
      for (int j = 0; j < 8; ++j) {
        float4 vv = vrow[j];
        acc[hf * 32 + j * 4 + 0] += av * vv.x;
        acc[hf * 32 + j * 4 + 1] += av * vv.y;
        acc[hf * 32 + j * 4 + 2] += av * vv.z;
        acc[hf * 32 + j * 4 + 3] += av * vv.w;
      }
    }
  }
  int bh = b * HEADS + head;
  unsigned short* dst = qgb + ((size_t)(bh * LTOT + win * 64 + t)) * DH;
  unsigned short* dstT = qgT + (size_t)bh * DH * LTOT + (size_t)win * 64 + t;
#pragma unroll
  for (int j = 0; j < 32; ++j) {
    int d0 = w4 * 32 + j;
    unsigned short v0 = (unsigned short)bf16rne(acc[j]);
    unsigned short v1 = (unsigned short)bf16rne(acc[32 + j]);
    dst[d0] = v0;
    dst[128 + d0] = v1;
    dstT[(size_t)d0 * LTOT] = v0;
    dstT[(size_t)(128 + d0) * LTOT] = v1;
  }
}

// Global flash attention, split-K (ns = 2^lg ways), 4 waves/block, 16 q/wave.
// Two-phase pipeline: tile kt+1 global->regs overlapped with compute of kt.
__global__ __launch_bounds__(256, 2) void gattn_mfma(
    const unsigned short* __restrict__ qgb, const unsigned short* __restrict__ qgT,
    unsigned short* __restrict__ ogp, float2* __restrict__ ml, int lg) {
  __shared__ unsigned short krow[32 * 256];  // 16 KB, XOR-swizzled rows
  __shared__ unsigned short vt[256 * 32];    // 16 KB, [dim][key]
  __shared__ unsigned short plds[4 * 16 * 40];
  int bid = blockIdx.x;
  int nsm1 = (1 << lg) - 1;
  int split = bid & nsm1;
  int qt = (bid >> lg) & 63;
  int bh = bid >> (lg + 6);
  int ntile = 128 >> lg;
  int kt0 = split * ntile, kt1 = kt0 + ntile;
  int qtile = qt * 64;
  int tid = threadIdx.x;
  int wave = tid >> 6;
  int lane = tid & 63;
  int lrow = lane & 15;
  int g = lane >> 4;
  const unsigned short* base = qgb + (size_t)bh * LTOT * DH;
  const unsigned short* baseT = qgT + (size_t)bh * DH * LTOT;
  char* krowc = (char*)krow;
  char* vtc = (char*)vt;
  char* plc = (char*)plds + wave * 16 * 80;

  int qi = qtile + wave * 16 + lrow;
  bf16x8 qf[8];
#pragma unroll
  for (int s = 0; s < 8; ++s)
    qf[s] = *(const bf16x8*)(base + (size_t)qi * DH + s * 32 + g * 8);

  f32x4 acc[16];
#pragma unroll
  for (int f = 0; f < 16; ++f) acc[f] = (f32x4){0.f, 0.f, 0.f, 0.f};
  float m = -1e30f, l = 0.f;

  uint4 kr0, kr1, kr2, kr3, vr0, vr1, vr2, vr3;
  // staging index decode (per thread, constant across tiles)
  int skey = tid >> 5;          // 0..7  (pairs with +8i)
  int sdb = tid & 31;
  int sdim = tid >> 2;          // 0..63 (pairs with +64i)
  int sch = tid & 3;

#define LOADT(KT)                                                               \
  {                                                                             \
    const unsigned short* kb = base + (size_t)(KT) * 32 * DH;                   \
    kr0 = *(const uint4*)(kb + (skey + 0) * DH + sdb * 8);                      \
    kr1 = *(const uint4*)(kb + (skey + 8) * DH + sdb * 8);                      \
    kr2 = *(const uint4*)(kb + (skey + 16) * DH + sdb * 8);                     \
    kr3 = *(const uint4*)(kb + (skey + 24) * DH + sdb * 8);                     \
    const unsigned short* vb = baseT + (size_t)(KT) * 32 + sch * 8;             \
    vr0 = *(const uint4*)(vb + (size_t)(sdim + 0) * LTOT);                      \
    vr1 = *(const uint4*)(vb + (size_t)(sdim + 64) * LTOT);                     \
    vr2 = *(const uint4*)(vb + (size_t)(sdim + 128) * LTOT);                    \
    vr3 = *(const uint4*)(vb + (size_t)(sdim + 192) * LTOT);                    \
  }

  LOADT(kt0);
  for (int kt = kt0; kt < kt1; ++kt) {
    __syncthreads();  // all waves done reading LDS of previous tile
    // ---- write staged regs -> LDS ----
    *(uint4*)(krowc + (skey + 0) * 512 + ((sdb * 16) ^ (((skey + 0) & 7) << 4))) = kr0;
    *(uint4*)(krowc + (skey + 8) * 512 + ((sdb * 16) ^ (((skey + 8) & 7) << 4))) = kr1;
    *(uint4*)(krowc + (skey + 16) * 512 + ((sdb * 16) ^ (((skey + 16) & 7) << 4))) = kr2;
    *(uint4*)(krowc + (skey + 24) * 512 + ((sdb * 16) ^ (((skey + 24) & 7) << 4))) = kr3;
    *(uint4*)(vtc + (sdim + 0) * 64 + sch * 16) = vr0;
    *(uint4*)(vtc + (sdim + 64) * 64 + sch * 16) = vr1;
    *(uint4*)(vtc + (sdim + 128) * 64 + sch * 16) = vr2;
    *(uint4*)(vtc + (sdim + 192) * 64 + sch * 16) = vr3;
    // ---- prefetch next tile into regs (latency hides under compute) ----
    if (kt + 1 < kt1) LOADT(kt + 1);
    __syncthreads();  // staged LDS visible
    // ---- S^T = K * Q^T (16 MFMAs, 4 independent chains) ----
    f32x4 s0a = (f32x4){0.f, 0.f, 0.f, 0.f}, s0b = s0a, s1a = s0a, s1b = s0a;
    int key0 = lrow, key1 = 16 + lrow;
    int sw = (lrow & 7) << 4;
    __builtin_amdgcn_s_setprio(1);
#pragma unroll
    for (int s = 0; s < 4; ++s) {
      bf16x8 k0 = *(const bf16x8*)(krowc + key0 * 512 + ((g * 16 + 64 * s) ^ sw));
      s0a = __builtin_amdgcn_mfma_f32_16x16x32_bf16(k0, qf[s], s0a, 0, 0, 0);
      bf16x8 k0b = *(const bf16x8*)(krowc + key0 * 512 + ((g * 16 + 64 * (s + 4)) ^ sw));
      s0b = __builtin_amdgcn_mfma_f32_16x16x32_bf16(k0b, qf[s + 4], s0b, 0, 0, 0);
      bf16x8 k1 = *(const bf16x8*)(krowc + key1 * 512 + ((g * 16 + 64 * s) ^ sw));
      s1a = __builtin_amdgcn_mfma_f32_16x16x32_bf16(k1, qf[s], s1a, 0, 0, 0);
      bf16x8 k1b = *(const bf16x8*)(krowc + key1 * 512 + ((g * 16 + 64 * (s + 4)) ^ sw));
      s1b = __builtin_amdgcn_mfma_f32_16x16x32_bf16(k1b, qf[s + 4], s1b, 0, 0, 0);
    }
    __builtin_amdgcn_s_setprio(0);
    f32x4 st0 = s0a + s0b;
    f32x4 st1 = s1a + s1b;
    // ---- online softmax with deferred rescale (thr=6) ----
    float tmax = -1e30f;
#pragma unroll
    for (int r = 0; r < 4; ++r) {
      tmax = fmaxf(tmax, st0[r]);
      tmax = fmaxf(tmax, st1[r]);
    }
    tmax = fmaxf(tmax, __shfl_xor(tmax, 16, 64));
    tmax = fmaxf(tmax, __shfl_xor(tmax, 32, 64));
    float sm = tmax * SCALE;
    if (__any(sm > m + 6.f)) {
      float mn = fmaxf(m, sm);
      float corr = __expf(m - mn);
#pragma unroll
      for (int f = 0; f < 16; ++f) {
        acc[f][0] *= corr; acc[f][1] *= corr;
        acc[f][2] *= corr; acc[f][3] *= corr;
      }
      l *= corr;
      m = mn;
    }
    float p[8];
    float psum = 0.f;
#pragma unroll
    for (int r = 0; r < 4; ++r) {
      p[r] = __expf(st0[r] * SCALE - m);
      p[4 + r] = __expf(st1[r] * SCALE - m);
      psum += p[r] + p[4 + r];
    }
    psum += __shfl_xor(psum, 16, 64);
    psum += __shfl_xor(psum, 32, 64);
    l += psum;
    // ---- write P^T (bf16) to per-wave LDS: plds[query][key] ----
    {
      uint2 pk0, pk1;
      pk0.x = bf16rne(p[0]) | (bf16rne(p[1]) << 16);
      pk0.y = bf16rne(p[2]) | (bf16rne(p[3]) << 16);
      pk1.x = bf16rne(p[4]) | (bf16rne(p[5]) << 16);
      pk1.y = bf16rne(p[6]) | (bf16rne(p[7]) << 16);
      *(uint2*)(plc + lrow * 80 + g * 8) = pk0;
      *(uint2*)(plc + lrow * 80 + 32 + g * 8) = pk1;
    }
    asm volatile("s_waitcnt lgkmcnt(0)" ::: "memory");
    // ---- O^T += V^T * P (16 MFMAs) ----
    bf16x8 pf = *(const bf16x8*)(plc + lrow * 80 + g * 16);
    __builtin_amdgcn_s_setprio(1);
#pragma unroll
    for (int f = 0; f < 16; ++f) {
      int dim = f * 16 + lrow;
      bf16x8 vf = *(const bf16x8*)(vtc + dim * 64 + g * 16);
      acc[f] = __builtin_amdgcn_mfma_f32_16x16x32_bf16(vf, pf, acc[f], 0, 0, 0);
    }
    __builtin_amdgcn_s_setprio(0);
  }
#undef LOADT
  // ---- epilogue: store unnormalized partial O as bf16 + (m,l) ----
  unsigned short* dstp = ogp + ((size_t)(split * 4 + bh) * LTOT + qi) * DH;
#pragma unroll
  for (int f = 0; f < 16; ++f) {
    uint2 pk;
    pk.x = bf16rne(acc[f][0]) | (bf16rne(acc[f][1]) << 16);
    pk.y = bf16rne(acc[f][2]) | (bf16rne(acc[f][3]) << 16);
    *(uint2*)(dstp + f * 16 + g * 4) = pk;
  }
  if (g == 0) ml[(size_t)(split * 4 + bh) * LTOT + qi] = make_float2(m, l);
}

// Per-query combine weights across ns key-splits.
__global__ __launch_bounds__(256) void comb_kernel(
    const float2* __restrict__ ml, float* __restrict__ wcomb, int ns) {
  int idx = blockIdx.x * 256 + threadIdx.x;  // 16384 = 4bh * 4096q
  float M = -1e30f;
  for (int s = 0; s < ns; ++s) M = fmaxf(M, ml[s * 16384 + idx].x);
  float D = 0.f;
  for (int s = 0; s < ns; ++s) {
    float2 a = ml[s * 16384 + idx];
    D += a.y * __expf(a.x - M);
  }
  float r = 1.f / D;
  for (int s = 0; s < ns; ++s)
    wcomb[s * 16384 + idx] = __expf(ml[s * 16384 + idx].x - M) * r;
}

// Combine splits + overlap-add gather + crop -> crop (B,C,64)
__global__ __launch_bounds__(256) void overlap_kernel(
    const unsigned short* __restrict__ ogp, const float* __restrict__ wcomb,
    float* __restrict__ crop, int ns) {
  int idx = blockIdx.x * 256 + threadIdx.x;
  int dim = idx & 255;
  int r = idx >> 8;
  int p = r & 63;
  int head = (r >> 6) & 1;
  int b = r >> 7;
  int bh = b * 2 + head;
  int y = p >> 3, x = p & 7;
  int py = y + TP, px = x + LP;
  int i0 = max(0, py - 7), i1 = min(7, py);
  int j0 = max(0, px - 7), j1 = min(7, px);
  float s = 0.f;
  for (int iw = i0; iw <= i1; ++iw)
    for (int jw = j0; jw <= j1; ++jw) {
      int tok = (py - iw) * 8 + (px - jw);
      int q = (iw * 8 + jw) * 64 + tok;
      int qidx = bh * 4096 + q;
      size_t e = (size_t)qidx * 256 + dim;
      for (int sp = 0; sp < ns; ++sp)
        s += wcomb[sp * 16384 + qidx] * bf2f(ogp[(size_t)sp * 4194304 + e]);
    }
  float cnt = (float)((i1 - i0 + 1) * (j1 - j0 + 1));
  crop[((size_t)b * CC + head * DH + dim) * 64 + p] = s / (cnt + 1e-6f);
}

// out = x_feat + a * (Wproj @ crop + bproj)
__global__ __launch_bounds__(256) void final_kernel(
    const float* __restrict__ crop, const float* __restrict__ Wp,
    const float* __restrict__ bp, const float* __restrict__ x_feat,
    const float* __restrict__ pa, float* __restrict__ out) {
  int blocksPerB = CC >> 2;
  int b = blockIdx.x / blocksPerB;
  int ob = blockIdx.x - b * blocksPerB;
  int o = ob * 4 + (threadIdx.x >> 6);
  int p = threadIdx.x & 63;
  float a = 2.f / (1.f + __expf(-pa[0]));
  const float* xb = crop + (size_t)b * CC * 64;
  const float* wr = Wp + (size_t)o * CC;
  float acc = 0.f;
#pragma unroll 8
  for (int c = 0; c < CC; ++c) acc += wr[c] * xb[c * 64 + p];
  size_t oi = ((size_t)b * CC + o) * 64 + p;
  out[oi] = x_feat[oi] + a * (acc + bp[o]);
}

extern "C" void kernel_launch(void* const* d_in, const int* in_sizes, int n_in,
                              void* d_out, int out_size, void* d_ws, size_t ws_size,
                              hipStream_t stream) {
  const float* x_feat = (const float*)d_in[0];
  const float* z_feat = (const float*)d_in[1];
  const float* Wqkv = (const float*)d_in[2];
  const float* bqkv = (const float*)d_in[3];
  const float* Wqkz = (const float*)d_in[4];
  const float* bqkz = (const float*)d_in[5];
  const float* Wproj = (const float*)d_in[6];
  const float* bproj = (const float*)d_in[7];
  const float* pa = (const float*)d_in[8];
  const float* pbeta = (const float*)d_in[9];
  float* ws = (float*)d_ws;
  // split-K width adaptive to workspace size (deterministic: ws_size is fixed)
  size_t need4 = (size_t)(4521984 + 4 * (2097152 + 32768)) * sizeof(float);
  int ns = (ws_size >= need4) ? 4 : 2;
  int lg = (ns == 4) ? 2 : 1;

  float* qkvx = ws;                                        // 196608 f
  float* qkz = ws + 196608;                                // 131072 f
  unsigned short* qgb = (unsigned short*)(ws + 327680);    // 2097152 f
  unsigned short* qgT = (unsigned short*)(ws + 2424832);   // 2097152 f
  unsigned short* ogp = (unsigned short*)(ws + 4521984);   // ns*2097152 f
  float2* ml = (float2*)(ws + 4521984 + ns * 2097152);     // ns*32768 f
  float* wcomb = ws + 196608;                              // alias qkz (dead after local_attn)
  float* crop = ws;                                        // alias qkvx (dead after local_attn)
  float* out = (float*)d_out;

  conv1x1_kernel<<<BB * (1536 / 4), 256, 0, stream>>>(x_feat, Wqkv, bqkv, qkvx, 1536);
  conv1x1_kernel<<<BB * (1024 / 4), 256, 0, stream>>>(z_feat, Wqkz, bqkz, qkz, 1024);
  local_attn_kernel<<<256, 256, 0, stream>>>(qkvx, qkz, pbeta, qgb, qgT);
  gattn_mfma<<<256 * ns, 256, 0, stream>>>(qgb, qgT, ogp, ml, lg);
  comb_kernel<<<64, 256, 0, stream>>>(ml, wcomb, ns);
  overlap_kernel<<<256, 256, 0, stream>>>(ogp, wcomb, crop, ns);
  final_kernel<<<BB * (CC / 4), 256, 0, stream>>>(crop, Wproj, bproj, x_feat, pa, out);
}

// Round 6
// 286.045 us; speedup vs baseline: 2.0862x; 1.1774x over previous
//
#include <hip/hip_runtime.h>
#include <math.h>

#define BB 2
#define CC 512
#define HEADS 2
#define DH 256
#define NWIN 64
#define LTOT 4096
#define TP 3
#define LP 3
#define SCALE 0.0625f

typedef short bf16x8 __attribute__((ext_vector_type(8)));
typedef float f32x4 __attribute__((ext_vector_type(4)));

__device__ __forceinline__ int refl8(int v) {
  v = v < 0 ? -v : v;
  return v >= 8 ? 14 - v : v;
}

__device__ __forceinline__ unsigned int bf16rne(float x) {
  unsigned int u = __float_as_uint(x);
  return (u + 0x7fffu + ((u >> 16) & 1u)) >> 16;
}

__device__ __forceinline__ float bf2f(unsigned short u) {
  return __uint_as_float(((unsigned int)u) << 16);
}

// Y[b,o,p] = sum_c W[o,c] * X[b,c,p] + bias[o]
__global__ __launch_bounds__(256) void conv1x1_kernel(
    const float* __restrict__ X, const float* __restrict__ Wm,
    const float* __restrict__ bias, float* __restrict__ Y, int Cout) {
  int blocksPerB = Cout >> 2;
  int b = blockIdx.x / blocksPerB;
  int ob = blockIdx.x - b * blocksPerB;
  int o = ob * 4 + (threadIdx.x >> 6);
  int p = threadIdx.x & 63;
  const float* xb = X + (size_t)b * CC * 64;
  const float* wr = Wm + (size_t)o * CC;
  float acc = 0.f;
#pragma unroll 8
  for (int c = 0; c < CC; ++c) acc += wr[c] * xb[c * 64 + p];
  Y[((size_t)b * Cout + o) * 64 + p] = acc + bias[o];
}

// One block per (b, win, head). Local window attention.
// Emits qgb (B,h,L,d) row-major bf16 AND qgT (B,h,d,L) dim-major bf16.
// kbuf is reused: K/KZ phases as [dd][tok] (128*64 floats), AV phase as
// [tok][dim-half] stride 132 (64*132 floats) — one 33.8 KB allocation.
__global__ __launch_bounds__(256) void local_attn_kernel(
    const float* __restrict__ qkvx, const float* __restrict__ qkz,
    const float* __restrict__ pbeta, unsigned short* __restrict__ qgb,
    unsigned short* __restrict__ qgT) {
  __shared__ float kbuf[64 * 132];  // 33792 f: >= 128*64 for K phases
  __shared__ float att[64 * 65];
  __shared__ float red[4 * 64];
  int bid = blockIdx.x;
  int b = bid >> 7;
  int win = (bid & 127) >> 1;
  int head = bid & 1;
  int tid = threadIdx.x;
  int t = tid & 63;
  int w4 = tid >> 6;
  int wi = win >> 3, wj = win & 7;
  int ry = refl8(wi + (t >> 3) - TP);
  int rx = refl8(wj + (t & 7) - LP);
  int pix = ry * 8 + rx;
  float beta = log1pf(__expf(pbeta[0])) + 1e-6f;

  const float* qxb = qkvx + (size_t)(b * 1536 + head * DH) * 64;
  const float* kxb = qkvx + (size_t)(b * 1536 + 512 + head * DH) * 64;
  const float* vxb = qkvx + (size_t)(b * 1536 + 1024 + head * DH) * 64;
  const float* qzb = qkz + (size_t)(b * 1024 + head * DH) * 64;
  const float* kzb = qkz + (size_t)(b * 1024 + 512 + head * DH) * 64;

  float dots[16];
#pragma unroll
  for (int s = 0; s < 16; ++s) dots[s] = 0.f;
#pragma unroll
  for (int hf = 0; hf < 2; ++hf) {
    __syncthreads();
    for (int i = 0; i < 32; ++i) {
      int dd = i * 4 + w4;
      kbuf[dd * 64 + t] = kxb[(hf * 128 + dd) * 64 + pix];
    }
    __syncthreads();
    for (int dd = 0; dd < 128; ++dd) {
      float qv = qxb[(hf * 128 + dd) * 64 + pix];
#pragma unroll
      for (int s = 0; s < 16; ++s)
        dots[s] += qv * kbuf[dd * 64 + w4 * 16 + s];
    }
  }
#pragma unroll
  for (int s = 0; s < 16; ++s) att[t * 65 + w4 * 16 + s] = dots[s];
#pragma unroll
  for (int s = 0; s < 16; ++s) dots[s] = 0.f;
#pragma unroll
  for (int hf = 0; hf < 2; ++hf) {
    __syncthreads();
    for (int i = 0; i < 32; ++i) {
      int dd = i * 4 + w4;
      kbuf[dd * 64 + t] = kzb[(hf * 128 + dd) * 64 + pix];
    }
    __syncthreads();
    for (int dd = 0; dd < 128; ++dd) {
      float qv = qzb[(hf * 128 + dd) * 64 + pix];
#pragma unroll
      for (int s = 0; s < 16; ++s)
        dots[s] += qv * kbuf[dd * 64 + w4 * 16 + s];
    }
  }
  // combine logits in regs, block-parallel softmax
  float vals[16];
  __syncthreads();
#pragma unroll
  for (int s = 0; s < 16; ++s)
    vals[s] = SCALE * (att[t * 65 + w4 * 16 + s] + beta * dots[s]);
  float mymax = -1e30f;
#pragma unroll
  for (int s = 0; s < 16; ++s) mymax = fmaxf(mymax, vals[s]);
  red[w4 * 64 + t] = mymax;
  __syncthreads();
  float m = fmaxf(fmaxf(red[t], red[64 + t]), fmaxf(red[128 + t], red[192 + t]));
  float mysum = 0.f;
#pragma unroll
  for (int s = 0; s < 16; ++s) {
    float e = __expf(vals[s] - m);
    vals[s] = e;
    mysum += e;
  }
  __syncthreads();
  red[w4 * 64 + t] = mysum;
  __syncthreads();
  float den = red[t] + red[64 + t] + red[128 + t] + red[192 + t];
  float rr = 1.f / den;
#pragma unroll
  for (int s = 0; s < 16; ++s) att[t * 65 + w4 * 16 + s] = vals[s] * rr;

  float acc[64];
#pragma unroll
  for (int j = 0; j < 64; ++j) acc[j] = 0.f;
#pragma unroll
  for (int hf = 0; hf < 2; ++hf) {
    __syncthreads();
    for (int i = 0; i < 32; ++i) {
      int dd = i * 4 + w4;
      kbuf[t * 132 + dd] = vxb[(hf * 128 + dd) * 64 + pix];  // [tok][dim-half]
    }
    __syncthreads();
    for (int s = 0; s < 64; ++s) {
      float av = att[t * 65 + s];
      const float4* vrow = (const float4*)&kbuf[s * 132 + w4 * 32];
#pragma unroll
      for (int j = 0; j < 8; ++j) {
        float4 vv = vrow[j];
        acc[hf * 32 + j * 4 + 0] += av * vv.x;
        acc[hf * 32 + j * 4 + 1] += av * vv.y;
        acc[hf * 32 + j * 4 + 2] += av * vv.z;
        acc[hf * 32 + j * 4 + 3] += av * vv.w;
      }
    }
  }
  int bh = b * HEADS + head;
  unsigned short* dst = qgb + ((size_t)(bh * LTOT + win * 64 + t)) * DH;
  unsigned short* dstT = qgT + (size_t)bh * DH * LTOT + (size_t)win * 64 + t;
#pragma unroll
  for (int j = 0; j < 32; ++j) {
    int d0 = w4 * 32 + j;
    unsigned short v0 = (unsigned short)bf16rne(acc[j]);
    unsigned short v1 = (unsigned short)bf16rne(acc[32 + j]);
    dst[d0] = v0;
    dst[128 + d0] = v1;
    dstT[(size_t)d0 * LTOT] = v0;
    dstT[(size_t)(128 + d0) * LTOT] = v1;
  }
}

// Global flash attention, split-K 2-way, 4 waves/block, 16 q/wave.
// Two-phase pipeline: tile kt+1 global->regs overlapped with compute of kt.
// vt stride = 80 B so PV ds_read_b128 is 2-way (free), not 8-way.
__global__ __launch_bounds__(256, 2) void gattn_mfma(
    const unsigned short* __restrict__ qgb, const unsigned short* __restrict__ qgT,
    unsigned short* __restrict__ ogp, float2* __restrict__ ml) {
  __shared__ unsigned short krow[32 * 256];  // 16 KB, XOR-swizzled rows
  __shared__ unsigned short vt[256 * 40];    // 20 KB, [dim][key], 80 B stride
  __shared__ unsigned short plds[4 * 16 * 40];
  int bid = blockIdx.x;
  int split = bid & 1;
  int qt = (bid >> 1) & 63;
  int bh = bid >> 7;
  int kt0 = split * 64, kt1 = kt0 + 64;
  int qtile = qt * 64;
  int tid = threadIdx.x;
  int wave = tid >> 6;
  int lane = tid & 63;
  int lrow = lane & 15;
  int g = lane >> 4;
  const unsigned short* base = qgb + (size_t)bh * LTOT * DH;
  const unsigned short* baseT = qgT + (size_t)bh * DH * LTOT;
  char* krowc = (char*)krow;
  char* vtc = (char*)vt;
  char* plc = (char*)plds + wave * 16 * 80;

  int qi = qtile + wave * 16 + lrow;
  bf16x8 qf[8];
#pragma unroll
  for (int s = 0; s < 8; ++s)
    qf[s] = *(const bf16x8*)(base + (size_t)qi * DH + s * 32 + g * 8);

  f32x4 acc[16];
#pragma unroll
  for (int f = 0; f < 16; ++f) acc[f] = (f32x4){0.f, 0.f, 0.f, 0.f};
  float m = -1e30f, l = 0.f;

  uint4 kr0, kr1, kr2, kr3, vr0, vr1, vr2, vr3;
  int skey = tid >> 5;  // 0..7
  int sdb = tid & 31;
  int sdim = tid >> 2;  // 0..63
  int sch = tid & 3;

#define LOADT(KT)                                                               \
  {                                                                             \
    const unsigned short* kb = base + (size_t)(KT) * 32 * DH;                   \
    kr0 = *(const uint4*)(kb + (skey + 0) * DH + sdb * 8);                      \
    kr1 = *(const uint4*)(kb + (skey + 8) * DH + sdb * 8);                      \
    kr2 = *(const uint4*)(kb + (skey + 16) * DH + sdb * 8);                     \
    kr3 = *(const uint4*)(kb + (skey + 24) * DH + sdb * 8);                     \
    const unsigned short* vb = baseT + (size_t)(KT) * 32 + sch * 8;             \
    vr0 = *(const uint4*)(vb + (size_t)(sdim + 0) * LTOT);                      \
    vr1 = *(const uint4*)(vb + (size_t)(sdim + 64) * LTOT);                     \
    vr2 = *(const uint4*)(vb + (size_t)(sdim + 128) * LTOT);                    \
    vr3 = *(const uint4*)(vb + (size_t)(sdim + 192) * LTOT);                    \
  }

  LOADT(kt0);
  for (int kt = kt0; kt < kt1; ++kt) {
    __syncthreads();  // all waves done reading LDS of previous tile
    // ---- write staged regs -> LDS ----
    *(uint4*)(krowc + (skey + 0) * 512 + ((sdb * 16) ^ (((skey + 0) & 7) << 4))) = kr0;
    *(uint4*)(krowc + (skey + 8) * 512 + ((sdb * 16) ^ (((skey + 8) & 7) << 4))) = kr1;
    *(uint4*)(krowc + (skey + 16) * 512 + ((sdb * 16) ^ (((skey + 16) & 7) << 4))) = kr2;
    *(uint4*)(krowc + (skey + 24) * 512 + ((sdb * 16) ^ (((skey + 24) & 7) << 4))) = kr3;
    *(uint4*)(vtc + (sdim + 0) * 80 + sch * 16) = vr0;
    *(uint4*)(vtc + (sdim + 64) * 80 + sch * 16) = vr1;
    *(uint4*)(vtc + (sdim + 128) * 80 + sch * 16) = vr2;
    *(uint4*)(vtc + (sdim + 192) * 80 + sch * 16) = vr3;
    // ---- prefetch next tile into regs (latency hides under compute) ----
    if (kt + 1 < kt1) LOADT(kt + 1);
    __syncthreads();  // staged LDS visible
    // ---- S^T = K * Q^T (16 MFMAs, 4 independent chains) ----
    f32x4 s0a = (f32x4){0.f, 0.f, 0.f, 0.f}, s0b = s0a, s1a = s0a, s1b = s0a;
    int key0 = lrow, key1 = 16 + lrow;
    int sw = (lrow & 7) << 4;
    __builtin_amdgcn_s_setprio(1);
#pragma unroll
    for (int s = 0; s < 4; ++s) {
      bf16x8 k0 = *(const bf16x8*)(krowc + key0 * 512 + ((g * 16 + 64 * s) ^ sw));
      s0a = __builtin_amdgcn_mfma_f32_16x16x32_bf16(k0, qf[s], s0a, 0, 0, 0);
      bf16x8 k0b = *(const bf16x8*)(krowc + key0 * 512 + ((g * 16 + 64 * (s + 4)) ^ sw));
      s0b = __builtin_amdgcn_mfma_f32_16x16x32_bf16(k0b, qf[s + 4], s0b, 0, 0, 0);
      bf16x8 k1 = *(const bf16x8*)(krowc + key1 * 512 + ((g * 16 + 64 * s) ^ sw));
      s1a = __builtin_amdgcn_mfma_f32_16x16x32_bf16(k1, qf[s], s1a, 0, 0, 0);
      bf16x8 k1b = *(const bf16x8*)(krowc + key1 * 512 + ((g * 16 + 64 * (s + 4)) ^ sw));
      s1b = __builtin_amdgcn_mfma_f32_16x16x32_bf16(k1b, qf[s + 4], s1b, 0, 0, 0);
    }
    __builtin_amdgcn_s_setprio(0);
    f32x4 st0 = s0a + s0b;
    f32x4 st1 = s1a + s1b;
    // ---- online softmax with deferred rescale (thr=6) ----
    float tmax = -1e30f;
#pragma unroll
    for (int r = 0; r < 4; ++r) {
      tmax = fmaxf(tmax, st0[r]);
      tmax = fmaxf(tmax, st1[r]);
    }
    tmax = fmaxf(tmax, __shfl_xor(tmax, 16, 64));
    tmax = fmaxf(tmax, __shfl_xor(tmax, 32, 64));
    float sm = tmax * SCALE;
    if (__any(sm > m + 6.f)) {
      float mn = fmaxf(m, sm);
      float corr = __expf(m - mn);
#pragma unroll
      for (int f = 0; f < 16; ++f) {
        acc[f][0] *= corr; acc[f][1] *= corr;
        acc[f][2] *= corr; acc[f][3] *= corr;
      }
      l *= corr;
      m = mn;
    }
    float p[8];
    float psum = 0.f;
#pragma unroll
    for (int r = 0; r < 4; ++r) {
      p[r] = __expf(st0[r] * SCALE - m);
      p[4 + r] = __expf(st1[r] * SCALE - m);
      psum += p[r] + p[4 + r];
    }
    psum += __shfl_xor(psum, 16, 64);
    psum += __shfl_xor(psum, 32, 64);
    l += psum;
    // ---- write P^T (bf16) to per-wave LDS: plds[query][key] ----
    {
      uint2 pk0, pk1;
      pk0.x = bf16rne(p[0]) | (bf16rne(p[1]) << 16);
      pk0.y = bf16rne(p[2]) | (bf16rne(p[3]) << 16);
      pk1.x = bf16rne(p[4]) | (bf16rne(p[5]) << 16);
      pk1.y = bf16rne(p[6]) | (bf16rne(p[7]) << 16);
      *(uint2*)(plc + lrow * 80 + g * 8) = pk0;
      *(uint2*)(plc + lrow * 80 + 32 + g * 8) = pk1;
    }
    asm volatile("s_waitcnt lgkmcnt(0)" ::: "memory");
    // ---- O^T += V^T * P (16 MFMAs) ----
    bf16x8 pf = *(const bf16x8*)(plc + lrow * 80 + g * 16);
    __builtin_amdgcn_s_setprio(1);
#pragma unroll
    for (int f = 0; f < 16; ++f) {
      int dim = f * 16 + lrow;
      bf16x8 vf = *(const bf16x8*)(vtc + dim * 80 + g * 16);
      acc[f] = __builtin_amdgcn_mfma_f32_16x16x32_bf16(vf, pf, acc[f], 0, 0, 0);
    }
    __builtin_amdgcn_s_setprio(0);
  }
#undef LOADT
  // ---- epilogue: store unnormalized partial O as bf16 + (m,l) ----
  unsigned short* dstp = ogp + ((size_t)(split * 4 + bh) * LTOT + qi) * DH;
#pragma unroll
  for (int f = 0; f < 16; ++f) {
    uint2 pk;
    pk.x = bf16rne(acc[f][0]) | (bf16rne(acc[f][1]) << 16);
    pk.y = bf16rne(acc[f][2]) | (bf16rne(acc[f][3]) << 16);
    *(uint2*)(dstp + f * 16 + g * 4) = pk;
  }
  if (g == 0) ml[(size_t)(split * 4 + bh) * LTOT + qi] = make_float2(m, l);
}

// Per-query combine weights across the 2 key-splits.
__global__ __launch_bounds__(256) void comb_kernel(
    const float2* __restrict__ ml, float* __restrict__ wcomb) {
  int idx = blockIdx.x * 256 + threadIdx.x;  // 16384 = 4bh * 4096q
  float2 a = ml[idx];
  float2 b = ml[16384 + idx];
  float M = fmaxf(a.x, b.x);
  float w0 = __expf(a.x - M), w1 = __expf(b.x - M);
  float r = 1.f / (a.y * w0 + b.y * w1);
  wcomb[idx] = w0 * r;
  wcomb[16384 + idx] = w1 * r;
}

// Combine splits + overlap-add gather + crop -> crop (B,C,64)
__global__ __launch_bounds__(256) void overlap_kernel(
    const unsigned short* __restrict__ ogp, const float* __restrict__ wcomb,
    float* __restrict__ crop) {
  int idx = blockIdx.x * 256 + threadIdx.x;
  int dim = idx & 255;
  int r = idx >> 8;
  int p = r & 63;
  int head = (r >> 6) & 1;
  int b = r >> 7;
  int bh = b * 2 + head;
  int y = p >> 3, x = p & 7;
  int py = y + TP, px = x + LP;
  int i0 = max(0, py - 7), i1 = min(7, py);
  int j0 = max(0, px - 7), j1 = min(7, px);
  float s = 0.f;
  for (int iw = i0; iw <= i1; ++iw)
    for (int jw = j0; jw <= j1; ++jw) {
      int tok = (py - iw) * 8 + (px - jw);
      int q = (iw * 8 + jw) * 64 + tok;
      int qidx = bh * 4096 + q;
      size_t e = (size_t)qidx * 256 + dim;
      s += wcomb[qidx] * bf2f(ogp[e]);
      s += wcomb[16384 + qidx] * bf2f(ogp[(size_t)4 * LTOT * DH + e]);
    }
  float cnt = (float)((i1 - i0 + 1) * (j1 - j0 + 1));
  crop[((size_t)b * CC + head * DH + dim) * 64 + p] = s / (cnt + 1e-6f);
}

// out = x_feat + a * (Wproj @ crop + bproj)
__global__ __launch_bounds__(256) void final_kernel(
    const float* __restrict__ crop, const float* __restrict__ Wp,
    const float* __restrict__ bp, const float* __restrict__ x_feat,
    const float* __restrict__ pa, float* __restrict__ out) {
  int blocksPerB = CC >> 2;
  int b = blockIdx.x / blocksPerB;
  int ob = blockIdx.x - b * blocksPerB;
  int o = ob * 4 + (threadIdx.x >> 6);
  int p = threadIdx.x & 63;
  float a = 2.f / (1.f + __expf(-pa[0]));
  const float* xb = crop + (size_t)b * CC * 64;
  const float* wr = Wp + (size_t)o * CC;
  float acc = 0.f;
#pragma unroll 8
  for (int c = 0; c < CC; ++c) acc += wr[c] * xb[c * 64 + p];
  size_t oi = ((size_t)b * CC + o) * 64 + p;
  out[oi] = x_feat[oi] + a * (acc + bp[o]);
}

extern "C" void kernel_launch(void* const* d_in, const int* in_sizes, int n_in,
                              void* d_out, int out_size, void* d_ws, size_t ws_size,
                              hipStream_t stream) {
  const float* x_feat = (const float*)d_in[0];
  const float* z_feat = (const float*)d_in[1];
  const float* Wqkv = (const float*)d_in[2];
  const float* bqkv = (const float*)d_in[3];
  const float* Wqkz = (const float*)d_in[4];
  const float* bqkz = (const float*)d_in[5];
  const float* Wproj = (const float*)d_in[6];
  const float* bproj = (const float*)d_in[7];
  const float* pa = (const float*)d_in[8];
  const float* pbeta = (const float*)d_in[9];
  float* ws = (float*)d_ws;
  float* qkvx = ws;                                        // 196608 f
  float* qkz = ws + 196608;                                // 131072 f
  unsigned short* qgb = (unsigned short*)(ws + 327680);    // 2097152 f
  unsigned short* qgT = (unsigned short*)(ws + 2424832);   // 2097152 f
  unsigned short* ogp = (unsigned short*)(ws + 4521984);   // 4194304 f (2 splits)
  float2* ml = (float2*)(ws + 8716288);                    // 65536 f
  float* wcomb = ws + 196608;                              // alias qkz (dead after local_attn)
  float* crop = ws;                                        // alias qkvx (dead after local_attn)
  float* out = (float*)d_out;

  conv1x1_kernel<<<BB * (1536 / 4), 256, 0, stream>>>(x_feat, Wqkv, bqkv, qkvx, 1536);
  conv1x1_kernel<<<BB * (1024 / 4), 256, 0, stream>>>(z_feat, Wqkz, bqkz, qkz, 1024);
  local_attn_kernel<<<256, 256, 0, stream>>>(qkvx, qkz, pbeta, qgb, qgT);
  gattn_mfma<<<512, 256, 0, stream>>>(qgb, qgT, ogp, ml);
  comb_kernel<<<64, 256, 0, stream>>>(ml, wcomb);
  overlap_kernel<<<256, 256, 0, stream>>>(ogp, wcomb, crop);
  final_kernel<<<BB * (CC / 4), 256, 0, stream>>>(crop, Wproj, bproj, x_feat, pa, out);
}